// Round 7
// baseline (226.786 us; speedup 1.0000x reference)
//
#include <hip/hip_runtime.h>
#include <stdint.h>

typedef _Float16 f16;
typedef __attribute__((ext_vector_type(8))) _Float16 f16x8;
typedef __attribute__((ext_vector_type(4))) float f32x4;
typedef __attribute__((ext_vector_type(16))) float f32x16;

#define BATCH 8192
#define INF   1024
#define OUTF  1024
#define KTOT  9216
#define NT    72   /* K-tiles of 64 per split (4608/64) */
#define CONV_BLOCKS 4608   /* 1024*1152/256 */

// ---------------------------------------------------------------------------
__device__ __forceinline__ void gload16(const void* g, void* l) {
  __builtin_amdgcn_global_load_lds(
      (const __attribute__((address_space(1))) uint32_t*)g,
      (__attribute__((address_space(3))) uint32_t*)l, 16, 0, 0);
}

// ---------------------------------------------------------------------------
// Fused prep: blocks [0, CONV_BLOCKS) convert W to f16; the rest build A.
// ---------------------------------------------------------------------------
__global__ __launch_bounds__(256) void fused_prep_kernel(
    const float* __restrict__ bw, const float* __restrict__ sw,
    const float* __restrict__ x, const float* __restrict__ grid,
    f16* __restrict__ Wb, f16* __restrict__ Abuf)
{
  int blk = blockIdx.x;
  if (blk < CONV_BLOCKS) {
    int idx = blk * 256 + threadIdx.x;   // [0, 1024*1152)
    int o = idx / 1152;
    int r = idx - o * 1152;
    int k8 = r * 8;
    const float* src = (k8 < INF) ? (bw + (size_t)o * INF + k8)
                                  : (sw + (size_t)o * (INF * 8) + (k8 - INF));
    float4 v0 = *(const float4*)src;
    float4 v1 = *(const float4*)(src + 4);
    f16x8 ov;
    ov[0] = (f16)v0.x; ov[1] = (f16)v0.y; ov[2] = (f16)v0.z; ov[3] = (f16)v0.w;
    ov[4] = (f16)v1.x; ov[5] = (f16)v1.y; ov[6] = (f16)v1.z; ov[7] = (f16)v1.w;
    *(f16x8*)(Wb + (size_t)o * KTOT + k8) = ov;
    return;
  }

  int q = (blk - CONV_BLOCKS) * 256 + threadIdx.x;   // one thread per 4 (b,i)
  int b = q >> 8;
  int i0 = (q & 255) << 2;
  float4 xv = *(const float4*)(x + ((size_t)b << 10) + i0);
  float xa[4] = {xv.x, xv.y, xv.z, xv.w};

  float g[12];
#pragma unroll
  for (int j = 0; j < 12; ++j) g[j] = grid[j];
  float H  = g[1] - g[0];
  float r1 = 1.0f / H;
  float r2 = 0.5f * r1;
  float r3 = (1.0f / 3.0f) * r1;

  f16 sil[4];
  f16x8 bas[4];
#pragma unroll
  for (int e = 0; e < 4; ++e) {
    float v = xa[e];
    sil[e] = (f16)(v / (1.0f + __expf(-v)));
    float xe = fminf(fmaxf(v, -0.99f), 0.99f);
    float Bv[11];
#pragma unroll
    for (int j = 0; j < 11; ++j) Bv[j] = (xe >= g[j] && xe < g[j + 1]) ? 1.0f : 0.0f;
#pragma unroll
    for (int j = 0; j < 10; ++j) Bv[j] = (xe - g[j]) * r1 * Bv[j] + (g[j + 2] - xe) * r1 * Bv[j + 1];
#pragma unroll
    for (int j = 0; j < 9; ++j)  Bv[j] = (xe - g[j]) * r2 * Bv[j] + (g[j + 3] - xe) * r2 * Bv[j + 1];
#pragma unroll
    for (int j = 0; j < 8; ++j)  Bv[j] = (xe - g[j]) * r3 * Bv[j] + (g[j + 4] - xe) * r3 * Bv[j + 1];
#pragma unroll
    for (int n = 0; n < 8; ++n) bas[e][n] = (f16)Bv[n];
  }
  f16* row = Abuf + (size_t)b * KTOT;
  *(uint64_t*)(row + i0) = *(const uint64_t*)sil;
  f16* bp = row + INF + (size_t)i0 * 8;
#pragma unroll
  for (int e = 0; e < 4; ++e) *(f16x8*)(bp + e * 8) = bas[e];
}

// ---------------------------------------------------------------------------
// GEMM: C[8192,1024] = A[8192,9216] * W[1024,9216]^T   (split-K = 2)
// 256x256 tile, BK=64 (4 k-steps of 16), 8 waves (2M x 4N, 128x64 each),
// 32x32x16 MFMA. Round-5 PROVEN sync skeleton (2 barriers/phase; every
// buffer's last ds_read completes >=1 lgkm-forced phase + >=3 barriers
// before the stage that overwrites it). All 8 B-frags of tile t are read
// in t-1's P4 so B-reads never share a region with B-stages.
// ---------------------------------------------------------------------------
#define LDA32(base, m, ks) (*(const f16x8*)((base) + (wr*128 + (m)*32 + l31)*64 + ((((ks)*2 + l5) ^ l7) * 8)))
#define LDB32(base, n, ks) (*(const f16x8*)((base) + (wcn*64 + (n)*32 + l31)*64 + ((((ks)*2 + l5) ^ l7) * 8)))

// 8 MFMAs, each acc touched once per cluster -> dep distance 8 (~64cy) ok
#define MFMA8(s, kk) do { \
  acc[0][0] = __builtin_amdgcn_mfma_f32_32x32x16_f16(af[s][0], bfk[kk][0], acc[0][0], 0, 0, 0); \
  acc[1][0] = __builtin_amdgcn_mfma_f32_32x32x16_f16(af[s][1], bfk[kk][0], acc[1][0], 0, 0, 0); \
  acc[2][0] = __builtin_amdgcn_mfma_f32_32x32x16_f16(af[s][2], bfk[kk][0], acc[2][0], 0, 0, 0); \
  acc[3][0] = __builtin_amdgcn_mfma_f32_32x32x16_f16(af[s][3], bfk[kk][0], acc[3][0], 0, 0, 0); \
  acc[0][1] = __builtin_amdgcn_mfma_f32_32x32x16_f16(af[s][0], bfk[kk][1], acc[0][1], 0, 0, 0); \
  acc[1][1] = __builtin_amdgcn_mfma_f32_32x32x16_f16(af[s][1], bfk[kk][1], acc[1][1], 0, 0, 0); \
  acc[2][1] = __builtin_amdgcn_mfma_f32_32x32x16_f16(af[s][2], bfk[kk][1], acc[2][1], 0, 0, 0); \
  acc[3][1] = __builtin_amdgcn_mfma_f32_32x32x16_f16(af[s][3], bfk[kk][1], acc[3][1], 0, 0, 0); \
} while (0)

#define READS_A(s, ks, bA_) do { \
  af[s][0] = LDA32(bA_, 0, ks); af[s][1] = LDA32(bA_, 1, ks); \
  af[s][2] = LDA32(bA_, 2, ks); af[s][3] = LDA32(bA_, 3, ks); } while (0)

#define READS_B_ALL(bB_) do { \
  bfk[0][0] = LDB32(bB_, 0, 0); bfk[0][1] = LDB32(bB_, 1, 0); \
  bfk[1][0] = LDB32(bB_, 0, 1); bfk[1][1] = LDB32(bB_, 1, 1); \
  bfk[2][0] = LDB32(bB_, 0, 2); bfk[2][1] = LDB32(bB_, 1, 2); \
  bfk[3][0] = LDB32(bB_, 0, 3); bfk[3][1] = LDB32(bB_, 1, 3); } while (0)

#define SCHED0 __builtin_amdgcn_sched_barrier(0)
#define SBARF  do { __builtin_amdgcn_s_barrier(); SCHED0; } while (0)

template <bool ATOMIC>
__global__ __launch_bounds__(512, 2) void kan_gemm_kernel(
    const f16* __restrict__ A, const f16* __restrict__ W,
    float* __restrict__ C, float* __restrict__ P1)
{
  __shared__ __align__(16) f16 lsA[2 * 256 * 64];   // 64 KB
  __shared__ __align__(16) f16 lsB[2 * 256 * 64];   // 64 KB

  const size_t K = KTOT;
  // L2-locality swizzle: the 4 wgs sharing an A-panel (same tm,split;
  // tn=0..3) land on ONE XCD -> A gets 4x L2 reuse.
  int bid = blockIdx.x;
  int xcd = bid & 7;
  int u   = bid >> 3;                      // 0..31 within XCD
  int tm  = xcd * 4 + (u & 3);
  int tn  = (u >> 2) & 3;
  int split = u >> 4;
  size_t kbase = (size_t)split * (NT * 64);

  int tid = threadIdx.x;
  int w = tid >> 6, l = tid & 63;
  int wr = w >> 2, wcn = w & 3;            // wave -> 128x64 output block
  int l31 = l & 31, l5 = l >> 5, l7 = l & 7;

  // staging addressing (pre-swizzled source chunk; linear LDS dest)
  int rh = tid >> 3;                       // row-in-half (0..63)
  int sc = (tid & 7) ^ (rh & 7);
  const f16* aSrc0 = A + (size_t)(tm * 256 + rh) * K + kbase + sc * 8;
  const f16* bSrc0 = W + (size_t)(tn * 256 + rh) * K + kbase + sc * 8;

  auto stage = [&](int h) {                // h: half idx; ty 0=Ah0,1=Ah1,2=Bh0,3=Bh1
    if (h >= 4 * NT) return;
    int tile = h >> 2, ty = h & 3, half = ty & 1;
    size_t koff = (size_t)tile * 64;
    if (ty < 2) {
      const f16* s = aSrc0 + (size_t)half * 128 * K + koff;
      f16* d = lsA + (tile & 1) * 16384 + half * 8192 + w * 512;
      gload16(s, d);
      gload16(s + 64 * K, d + 4096);
    } else {
      const f16* s = bSrc0 + (size_t)half * 128 * K + koff;
      f16* d = lsB + (tile & 1) * 16384 + half * 8192 + w * 512;
      gload16(s, d);
      gload16(s + 64 * K, d + 4096);
    }
  };

  f16x8 af[2][4];      // A: 2 alternating k-step slots
  f16x8 bfk[4][2];     // B: whole tile (4 k-steps), read once per tile in P4
  f32x16 acc[4][2] = {};

  // ---- prologue: B(0) 4, A(0) 4, B(1) 4 loads; drain tile0; read frags
  stage(2); stage(3); stage(0); stage(1); stage(6); stage(7);
  asm volatile("s_waitcnt vmcnt(4)" ::: "memory");   // B0,A0 landed; B1 in flight
  SBARF;
  READS_B_ALL(lsB);
  READS_A(0, 0, lsA);
  READS_A(1, 1, lsA);

  for (int t = 0; t < NT; ++t) {
    const f16* bA  = lsA + (t & 1) * 16384;
    const f16* bA1 = lsA + ((t + 1) & 1) * 16384;
    const f16* bB1 = lsB + ((t + 1) & 1) * 16384;
    int h1 = 4 * (t + 1), h2 = 4 * (t + 2);

    // P1: stage A(t+1) -> opposite buf | MFMA ks0 | read A ks2
    stage(h1 + 0); stage(h1 + 1);
    SBARF;
    __builtin_amdgcn_s_setprio(1);
    MFMA8(0, 0);
    __builtin_amdgcn_s_setprio(0);
    READS_A(0, 2, bA);
    SBARF;

    // P2: stage Bh0(t+2) -> cur buf (B-reads of cur finished t-1 P4) | MFMA ks1 | read A ks3
    stage(h2 + 2);
    SBARF;
    __builtin_amdgcn_s_setprio(1);
    MFMA8(1, 1);
    __builtin_amdgcn_s_setprio(0);
    READS_A(1, 3, bA);
    SBARF;

    // P3: stage Bh1(t+2) | MFMA ks2
    stage(h2 + 3);
    SBARF;
    __builtin_amdgcn_s_setprio(1);
    MFMA8(0, 2);
    __builtin_amdgcn_s_setprio(0);
    SBARF;

    // P4: counted vmcnt (A(t+1)+B(t+1) landed, B(t+2) in flight) | MFMA ks3
    //     | read ALL frags of tile t+1
    if (t < NT - 2)       asm volatile("s_waitcnt vmcnt(4)" ::: "memory");
    else if (t == NT - 2) asm volatile("s_waitcnt vmcnt(0)" ::: "memory");
    SBARF;
    __builtin_amdgcn_s_setprio(1);
    MFMA8(1, 3);
    __builtin_amdgcn_s_setprio(0);
    if (t < NT - 1) {
      READS_B_ALL(bB1);
      READS_A(0, 0, bA1);
      READS_A(1, 1, bA1);
    }
    SBARF;
  }

  // ---- epilogue: 32x32 C/D layout col=l&31, row=(r&3)+8*(r>>2)+4*(l>>5) ----
  int colBase  = tn * 256 + wcn * 64 + l31;
  int rowBase0 = tm * 256 + wr * 128 + 4 * l5;
  float* dst = ATOMIC ? C : (split ? P1 : C);
#pragma unroll
  for (int m = 0; m < 4; ++m)
#pragma unroll
    for (int n = 0; n < 2; ++n) {
      int col = colBase + n * 32;
#pragma unroll
      for (int r = 0; r < 16; ++r) {
        int row = rowBase0 + m * 32 + (r & 3) + 8 * (r >> 2);
        if (ATOMIC) atomicAdd(&dst[(size_t)row * OUTF + col], acc[m][n][r]);
        else        dst[(size_t)row * OUTF + col] = acc[m][n][r];
      }
    }
}

// ---------------------------------------------------------------------------
__global__ __launch_bounds__(256) void reduce_kernel(
    float* __restrict__ out, const float* __restrict__ p)
{
  size_t i = ((size_t)blockIdx.x * 256 + threadIdx.x) * 4;
  f32x4 a = *(f32x4*)(out + i);
  f32x4 b = *(const f32x4*)(p + i);
  a += b;
  *(f32x4*)(out + i) = a;
}

// ---------------------------------------------------------------------------
extern "C" void kernel_launch(void* const* d_in, const int* in_sizes, int n_in,
                              void* d_out, int out_size, void* d_ws, size_t ws_size,
                              hipStream_t stream)
{
  const float* x  = (const float*)d_in[0];
  const float* bw = (const float*)d_in[1];
  const float* sw = (const float*)d_in[2];
  const float* gr = (const float*)d_in[3];
  float* out = (float*)d_out;

  f16* Wb = (f16*)d_ws;
  size_t wBytes = (size_t)OUTF * KTOT * sizeof(f16);      // 18.9 MB
  f16* Abuf = (f16*)((char*)d_ws + wBytes);               // 151 MB
  size_t aBytes = (size_t)BATCH * KTOT * sizeof(f16);
  size_t oBytes = (size_t)BATCH * OUTF * sizeof(float);   // 33.5 MB

  int prepBlocks = (BATCH * INF / 4) / 256;               // 8192
  fused_prep_kernel<<<CONV_BLOCKS + prepBlocks, 256, 0, stream>>>(
      bw, sw, x, gr, Wb, Abuf);

  if (ws_size >= wBytes + aBytes + oBytes) {
    float* P1 = (float*)((char*)d_ws + wBytes + aBytes);
    kan_gemm_kernel<false><<<256, 512, 0, stream>>>(Abuf, Wb, out, P1);
    reduce_kernel<<<(int)(oBytes / sizeof(float) / 4 / 256), 256, 0, stream>>>(out, P1);
  } else {
    hipMemsetAsync(d_out, 0, oBytes, stream);
    kan_gemm_kernel<true><<<256, 512, 0, stream>>>(Abuf, Wb, out, nullptr);
  }
}

// Round 8
// 203.670 us; speedup vs baseline: 1.1135x; 1.1135x over previous
//
#include <hip/hip_runtime.h>
#include <stdint.h>

typedef _Float16 f16;
typedef __attribute__((ext_vector_type(8))) _Float16 f16x8;
typedef __attribute__((ext_vector_type(4))) float f32x4;

#define BATCH 8192
#define INF   1024
#define OUTF  1024
#define KTOT  9216
#define NT    72   /* K-tiles of 64 per split (4608/64) */
#define CONV_BLOCKS 4608   /* 1024*1152/256 */

// ---------------------------------------------------------------------------
__device__ __forceinline__ void gload16(const void* g, void* l) {
  __builtin_amdgcn_global_load_lds(
      (const __attribute__((address_space(1))) uint32_t*)g,
      (__attribute__((address_space(3))) uint32_t*)l, 16, 0, 0);
}

// ---------------------------------------------------------------------------
// Fused prep: blocks [0, CONV_BLOCKS) convert W to f16; the rest build A.
// ---------------------------------------------------------------------------
__global__ __launch_bounds__(256) void fused_prep_kernel(
    const float* __restrict__ bw, const float* __restrict__ sw,
    const float* __restrict__ x, const float* __restrict__ grid,
    f16* __restrict__ Wb, f16* __restrict__ Abuf)
{
  int blk = blockIdx.x;
  if (blk < CONV_BLOCKS) {
    int idx = blk * 256 + threadIdx.x;   // [0, 1024*1152)
    int o = idx / 1152;
    int r = idx - o * 1152;
    int k8 = r * 8;
    const float* src = (k8 < INF) ? (bw + (size_t)o * INF + k8)
                                  : (sw + (size_t)o * (INF * 8) + (k8 - INF));
    float4 v0 = *(const float4*)src;
    float4 v1 = *(const float4*)(src + 4);
    f16x8 ov;
    ov[0] = (f16)v0.x; ov[1] = (f16)v0.y; ov[2] = (f16)v0.z; ov[3] = (f16)v0.w;
    ov[4] = (f16)v1.x; ov[5] = (f16)v1.y; ov[6] = (f16)v1.z; ov[7] = (f16)v1.w;
    *(f16x8*)(Wb + (size_t)o * KTOT + k8) = ov;
    return;
  }

  int q = (blk - CONV_BLOCKS) * 256 + threadIdx.x;   // one thread per 4 (b,i)
  int b = q >> 8;
  int i0 = (q & 255) << 2;
  float4 xv = *(const float4*)(x + ((size_t)b << 10) + i0);
  float xa[4] = {xv.x, xv.y, xv.z, xv.w};

  float g[12];
#pragma unroll
  for (int j = 0; j < 12; ++j) g[j] = grid[j];
  float H  = g[1] - g[0];
  float r1 = 1.0f / H;
  float r2 = 0.5f * r1;
  float r3 = (1.0f / 3.0f) * r1;

  f16 sil[4];
  f16x8 bas[4];
#pragma unroll
  for (int e = 0; e < 4; ++e) {
    float v = xa[e];
    sil[e] = (f16)(v / (1.0f + __expf(-v)));
    float xe = fminf(fmaxf(v, -0.99f), 0.99f);
    float Bv[11];
#pragma unroll
    for (int j = 0; j < 11; ++j) Bv[j] = (xe >= g[j] && xe < g[j + 1]) ? 1.0f : 0.0f;
#pragma unroll
    for (int j = 0; j < 10; ++j) Bv[j] = (xe - g[j]) * r1 * Bv[j] + (g[j + 2] - xe) * r1 * Bv[j + 1];
#pragma unroll
    for (int j = 0; j < 9; ++j)  Bv[j] = (xe - g[j]) * r2 * Bv[j] + (g[j + 3] - xe) * r2 * Bv[j + 1];
#pragma unroll
    for (int j = 0; j < 8; ++j)  Bv[j] = (xe - g[j]) * r3 * Bv[j] + (g[j + 4] - xe) * r3 * Bv[j + 1];
#pragma unroll
    for (int n = 0; n < 8; ++n) bas[e][n] = (f16)Bv[n];
  }
  f16* row = Abuf + (size_t)b * KTOT;
  *(uint64_t*)(row + i0) = *(const uint64_t*)sil;
  f16* bp = row + INF + (size_t)i0 * 8;
#pragma unroll
  for (int e = 0; e < 4; ++e) *(f16x8*)(bp + e * 8) = bas[e];
}

// ---------------------------------------------------------------------------
// GEMM: C[8192,1024] = A[8192,9216] * W[1024,9216]^T   (split-K = 2)
// 256x256 tile, BK=64, 8 waves (2M x 4N, 128x64 each), 16x16x32 MFMA
// (PROVEN 0-conflict LDS read pattern), 4-phase R5 sync skeleton,
// L2-locality XCD swizzle (PROVEN -50% FETCH), reads smoothed 8/4/4/8
// with s0-consumed reads front-loaded before each MFMA cluster.
// ---------------------------------------------------------------------------
#define LDA(base, m, s) (*(const f16x8*)((base) + ((wr*128 + (m)*16 + la) * 64 + ((((s)*4 + lb) ^ lasw) * 8))))
#define LDB(base, n, s) (*(const f16x8*)((base) + ((wcn*64 + (n)*16 + la) * 64 + ((((s)*4 + lb) ^ lasw) * 8))))

#define MFMA1(m, n, s) acc[m][n] = __builtin_amdgcn_mfma_f32_16x16x32_f16(af[m][s], bf[n][s], acc[m][n], 0, 0, 0)
// 8-MFMA half-cluster: same-acc reuse distance 8 across the two halves
#define MFMA_S0(m0) do { \
  MFMA1(m0,0,0);   MFMA1(m0,1,0);   MFMA1(m0,2,0);   MFMA1(m0,3,0); \
  MFMA1(m0+1,0,0); MFMA1(m0+1,1,0); MFMA1(m0+1,2,0); MFMA1(m0+1,3,0); } while (0)
#define MFMA_S1(m0) do { \
  MFMA1(m0,0,1);   MFMA1(m0,1,1);   MFMA1(m0,2,1);   MFMA1(m0,3,1); \
  MFMA1(m0+1,0,1); MFMA1(m0+1,1,1); MFMA1(m0+1,2,1); MFMA1(m0+1,3,1); } while (0)

#define SCHED0 __builtin_amdgcn_sched_barrier(0)
// barrier + code-motion fence: nothing crosses a barrier at compile time
#define SBARF do { __builtin_amdgcn_s_barrier(); SCHED0; } while (0)

template <bool ATOMIC>
__global__ __launch_bounds__(512, 2) void kan_gemm_kernel(
    const f16* __restrict__ A, const f16* __restrict__ W,
    float* __restrict__ C, float* __restrict__ P1)
{
  __shared__ __align__(16) f16 lsA[2 * 256 * 64];   // 64 KB
  __shared__ __align__(16) f16 lsB[2 * 256 * 64];   // 64 KB

  const size_t K = KTOT;
  // L2-locality swizzle: the 4 wgs sharing an A-panel (same tm,split;
  // tn=0..3) land on ONE XCD -> A gets 4x L2 reuse (FETCH 304->147MB, R7).
  int bid = blockIdx.x;
  int xcd = bid & 7;
  int u   = bid >> 3;                      // 0..31 within XCD
  int tm  = xcd * 4 + (u & 3);
  int tn  = (u >> 2) & 3;
  int split = u >> 4;
  size_t kbase = (size_t)split * (NT * 64);

  int tid = threadIdx.x;
  int w = tid >> 6, l = tid & 63;
  int wr = w >> 2, wcn = w & 3;            // wave -> 128x64 output block
  int la = l & 15, lb = l >> 4, lasw = la & 7;

  // staging addressing (pre-swizzled source chunk; linear LDS dest)
  int rh = tid >> 3;                       // row-in-half (0..63)
  int sc = (tid & 7) ^ (rh & 7);
  const f16* aSrc0 = A + (size_t)(tm * 256 + rh) * K + kbase + sc * 8;
  const f16* bSrc0 = W + (size_t)(tn * 256 + rh) * K + kbase + sc * 8;

  auto stage = [&](int h) {                // h: half idx; ty 0=Ah0,1=Ah1,2=Bh0,3=Bh1
    if (h >= 4 * NT) return;
    int tile = h >> 2, ty = h & 3, half = ty & 1;
    size_t koff = (size_t)tile * 64;
    if (ty < 2) {
      const f16* s = aSrc0 + (size_t)half * 128 * K + koff;
      f16* d = lsA + (tile & 1) * 16384 + half * 8192 + w * 512;
      gload16(s, d);
      gload16(s + 64 * K, d + 4096);
    } else {
      const f16* s = bSrc0 + (size_t)half * 128 * K + koff;
      f16* d = lsB + (tile & 1) * 16384 + half * 8192 + w * 512;
      gload16(s, d);
      gload16(s + 64 * K, d + 4096);
    }
  };

  f16x8 af[8][2], bf[4][2];
  f32x4 acc[8][4] = {};

  // ---- prologue: B(0),A(0),B(1) staged; drain tile0; pre-read af[0,1], bf[*][0]
  stage(2); stage(3); stage(0); stage(1); stage(6); stage(7);
  asm volatile("s_waitcnt vmcnt(4)" ::: "memory");
  SBARF;
  {
    const f16* bA = lsA; const f16* bB = lsB;
#pragma unroll
    for (int n = 0; n < 4; ++n) bf[n][0] = LDB(bB, n, 0);
    af[0][0] = LDA(bA, 0, 0); af[0][1] = LDA(bA, 0, 1);
    af[1][0] = LDA(bA, 1, 0); af[1][1] = LDA(bA, 1, 1);
  }

  for (int t = 0; t < NT; ++t) {
    const f16* bA  = lsA + (t & 1) * 16384;
    const f16* bB  = lsB + (t & 1) * 16384;
    const f16* bA1 = lsA + ((t + 1) & 1) * 16384;
    const f16* bB1 = lsB + ((t + 1) & 1) * 16384;
    int h1 = 4 * (t + 1), h2 = 4 * (t + 2);

    // P1: stage A(t+1) | front: bf[*][1](cur)+af[2,3][0] | S0 | af[2,3][1] | S1
    stage(h1 + 0); stage(h1 + 1);
    SBARF;
    __builtin_amdgcn_s_setprio(1);
    bf[0][1] = LDB(bB, 0, 1); bf[1][1] = LDB(bB, 1, 1);
    bf[2][1] = LDB(bB, 2, 1); bf[3][1] = LDB(bB, 3, 1);
    af[2][0] = LDA(bA, 2, 0); af[3][0] = LDA(bA, 3, 0);
    MFMA_S0(0);
    af[2][1] = LDA(bA, 2, 1); af[3][1] = LDA(bA, 3, 1);
    MFMA_S1(0);
    __builtin_amdgcn_s_setprio(0);
    SBARF;

    // P2: stage Bh0(t+2) | front: af[4,5][0] | S0 | af[4,5][1] | S1
    stage(h2 + 2);
    SBARF;
    __builtin_amdgcn_s_setprio(1);
    af[4][0] = LDA(bA, 4, 0); af[5][0] = LDA(bA, 5, 0);
    MFMA_S0(2);
    af[4][1] = LDA(bA, 4, 1); af[5][1] = LDA(bA, 5, 1);
    MFMA_S1(2);
    __builtin_amdgcn_s_setprio(0);
    SBARF;

    // P3: stage Bh1(t+2) | front: af[6,7][0] | S0 | af[6,7][1] | S1
    stage(h2 + 3);
    SBARF;
    __builtin_amdgcn_s_setprio(1);
    af[6][0] = LDA(bA, 6, 0); af[7][0] = LDA(bA, 7, 0);
    MFMA_S0(4);
    af[6][1] = LDA(bA, 6, 1); af[7][1] = LDA(bA, 7, 1);
    MFMA_S1(4);
    __builtin_amdgcn_s_setprio(0);
    SBARF;

    // P4: counted vmcnt | S0 | mid: bf[*][0]+af[0,1][*](t+1) | S1
    //     (bf[n][0](t+1) read AFTER S0(6) which consumes the old values)
    if (t < NT - 2)       asm volatile("s_waitcnt vmcnt(4)" ::: "memory");
    else if (t == NT - 2) asm volatile("s_waitcnt vmcnt(0)" ::: "memory");
    SBARF;
    __builtin_amdgcn_s_setprio(1);
    MFMA_S0(6);
    if (t < NT - 1) {
      bf[0][0] = LDB(bB1, 0, 0); bf[1][0] = LDB(bB1, 1, 0);
      bf[2][0] = LDB(bB1, 2, 0); bf[3][0] = LDB(bB1, 3, 0);
      af[0][0] = LDA(bA1, 0, 0); af[0][1] = LDA(bA1, 0, 1);
      af[1][0] = LDA(bA1, 1, 0); af[1][1] = LDA(bA1, 1, 1);
    }
    MFMA_S1(6);
    __builtin_amdgcn_s_setprio(0);
    SBARF;
  }

  // ---- epilogue ----
  int rowBase = tm * 256 + wr * 128 + lb * 4;
  int colBase = tn * 256 + wcn * 64 + la;
  float* dst = ATOMIC ? C : (split ? P1 : C);
#pragma unroll
  for (int m = 0; m < 8; ++m)
#pragma unroll
    for (int n = 0; n < 4; ++n) {
      int col = colBase + n * 16;
#pragma unroll
      for (int j = 0; j < 4; ++j) {
        int row = rowBase + m * 16 + j;
        if (ATOMIC) atomicAdd(&C[(size_t)row * OUTF + col], acc[m][n][j]);
        else        dst[(size_t)row * OUTF + col] = acc[m][n][j];
      }
    }
}

// ---------------------------------------------------------------------------
__global__ __launch_bounds__(256) void reduce_kernel(
    float* __restrict__ out, const float* __restrict__ p)
{
  size_t i = ((size_t)blockIdx.x * 256 + threadIdx.x) * 4;
  f32x4 a = *(f32x4*)(out + i);
  f32x4 b = *(const f32x4*)(p + i);
  a += b;
  *(f32x4*)(out + i) = a;
}

// ---------------------------------------------------------------------------
extern "C" void kernel_launch(void* const* d_in, const int* in_sizes, int n_in,
                              void* d_out, int out_size, void* d_ws, size_t ws_size,
                              hipStream_t stream)
{
  const float* x  = (const float*)d_in[0];
  const float* bw = (const float*)d_in[1];
  const float* sw = (const float*)d_in[2];
  const float* gr = (const float*)d_in[3];
  float* out = (float*)d_out;

  f16* Wb = (f16*)d_ws;
  size_t wBytes = (size_t)OUTF * KTOT * sizeof(f16);      // 18.9 MB
  f16* Abuf = (f16*)((char*)d_ws + wBytes);               // 151 MB
  size_t aBytes = (size_t)BATCH * KTOT * sizeof(f16);
  size_t oBytes = (size_t)BATCH * OUTF * sizeof(float);   // 33.5 MB

  int prepBlocks = (BATCH * INF / 4) / 256;               // 8192
  fused_prep_kernel<<<CONV_BLOCKS + prepBlocks, 256, 0, stream>>>(
      bw, sw, x, gr, Wb, Abuf);

  if (ws_size >= wBytes + aBytes + oBytes) {
    float* P1 = (float*)((char*)d_ws + wBytes + aBytes);
    kan_gemm_kernel<false><<<256, 512, 0, stream>>>(Abuf, Wb, out, P1);
    reduce_kernel<<<(int)(oBytes / sizeof(float) / 4 / 256), 256, 0, stream>>>(out, P1);
  } else {
    hipMemsetAsync(d_out, 0, oBytes, stream);
    kan_gemm_kernel<true><<<256, 512, 0, stream>>>(Abuf, Wb, out, nullptr);
  }
}